// Round 4
// baseline (414.217 us; speedup 1.0000x reference)
//
#include <hip/hip_runtime.h>

#define SEQ 1024
#define NH  16

typedef __attribute__((ext_vector_type(8))) short short8;
typedef __attribute__((ext_vector_type(4))) float floatx4;
typedef __attribute__((ext_vector_type(4))) unsigned short ushortx4;

// async global->LDS, 16B per lane; LDS dest = wave-uniform base + lane*16
#define GLDS16(gp, lp) __builtin_amdgcn_global_load_lds( \
    (const __attribute__((address_space(1))) void*)(gp), \
    (__attribute__((address_space(3))) void*)(lp), 16, 0, 0)

__device__ __forceinline__ unsigned short f2b(float f) {   // fp32 -> bf16 RNE
    union { float f; unsigned u; } v; v.f = f;
    unsigned r = (v.u + 0x7fffu + ((v.u >> 16) & 1u)) >> 16;
    return (unsigned short)r;
}
__device__ __forceinline__ float b2f(unsigned short h) {
    union { unsigned u; float f; } v; v.u = ((unsigned)h) << 16;
    return v.f;
}

// swizzled addr helper (element offsets in a 64-wide bf16 tile: 8 chunks of 16B/row)
#define TADDR(base, row, ch) ((base) + ((row) << 6) + ((((ch) ^ ((row) & 7))) << 3))

// ---------------- k0: fp32 -> bf16 casts ----------------
__global__ void cast_kernel(const float* __restrict__ hs, const float* __restrict__ W,
                            const float* __restrict__ E,
                            unsigned short* __restrict__ hsb,
                            unsigned short* __restrict__ Wb,
                            unsigned short* __restrict__ Eb)
{
    const int QH = 1048576, QW = 786432, QE = 32752;   // quads
    const int NT = QH + QW + QE;
    for (int q = blockIdx.x * 256 + threadIdx.x; q < NT; q += gridDim.x * 256) {
        const float* src; unsigned short* dst; int off;
        if (q < QH)           { src = hs; dst = hsb; off = q; }
        else if (q < QH + QW) { src = W;  dst = Wb;  off = q - QH; }
        else                  { src = E;  dst = Eb;  off = q - QH - QW; }
        const float4 v = *(const float4*)(src + (size_t)off * 4);
        ushortx4 o; o[0] = f2b(v.x); o[1] = f2b(v.y); o[2] = f2b(v.z); o[3] = f2b(v.w);
        *(ushortx4*)(dst + (size_t)off * 4) = o;
    }
}

// ---------------- k1: QKV projection, bf16 MFMA, NT layout ----------------
__global__ __launch_bounds__(256, 3) void qkv_gemm(
    const unsigned short* __restrict__ Ab, const unsigned short* __restrict__ Bb,
    const float* __restrict__ bias,
    unsigned short* __restrict__ Qb, unsigned short* __restrict__ Kb,
    unsigned short* __restrict__ Vt)
{
    __shared__ unsigned short sm[8192];          // A [0,4096), B [4096,8192) elems
    const int t = threadIdx.x, w = t >> 6;
    const int ln = t & 15, g = (t >> 4) & 3;
    const int wm = w >> 1, wn = w & 1;
    const int m0 = blockIdx.y << 7, o0 = blockIdx.x << 7;

    floatx4 acc[4][4];
#pragma unroll
    for (int i = 0; i < 4; ++i)
#pragma unroll
        for (int j = 0; j < 4; ++j) acc[i][j] = (floatx4){0.f, 0.f, 0.f, 0.f};

    auto stage = [&](int kb) {
#pragma unroll
        for (int p = 0; p < 2; ++p) {
            const int idx = (p << 8) + t;
            const int row = idx >> 2;
            const int c = (idx & 3) ^ ((row ^ (row >> 2)) & 3);
            GLDS16(Ab + (size_t)(m0 + row) * 1024 + kb + (c << 3),
                   (char*)sm + (p << 12) + (w << 10));
            GLDS16(Bb + (size_t)(o0 + row) * 1024 + kb + (c << 3),
                   (char*)sm + 8192 + (p << 12) + (w << 10));
        }
    };

    stage(0);
    for (int kb = 0;;) {
        __syncthreads();
        short8 af[4], bf_[4];
#pragma unroll
        for (int i = 0; i < 4; ++i) {
            const int r = (wm << 6) + (i << 4) + ln;
            af[i] = *(const short8*)&sm[(r << 5) + ((g ^ ((r ^ (r >> 2)) & 3)) << 3)];
        }
#pragma unroll
        for (int j = 0; j < 4; ++j) {
            const int r = (wn << 6) + (j << 4) + ln;
            bf_[j] = *(const short8*)&sm[4096 + (r << 5) + ((g ^ ((r ^ (r >> 2)) & 3)) << 3)];
        }
#pragma unroll
        for (int i = 0; i < 4; ++i)
#pragma unroll
            for (int j = 0; j < 4; ++j)
                acc[i][j] = __builtin_amdgcn_mfma_f32_16x16x32_bf16(af[i], bf_[j], acc[i][j], 0, 0, 0);
        kb += 32;
        if (kb >= 1024) break;
        __syncthreads();
        stage(kb);
    }

    const int which = o0 >> 10;     // 0=Q 1=K 2=V (block-uniform)
    float bj[4];
#pragma unroll
    for (int j = 0; j < 4; ++j) bj[j] = bias[o0 + (wn << 6) + (j << 4) + ln];

    if (which == 2) {               // V transposed: Vt[bh][d][s]
#pragma unroll
        for (int i = 0; i < 4; ++i) {
            const int m = m0 + (wm << 6) + (i << 4) + (g << 2);
            const int b = m >> 10, s = m & 1023;
#pragma unroll
            for (int j = 0; j < 4; ++j) {
                const int o = o0 + (wn << 6) + (j << 4) + ln;
                const int d = o & 63, hh = (o >> 6) & 15;
                ushortx4 pk;
#pragma unroll
                for (int q = 0; q < 4; ++q) pk[q] = f2b(acc[i][j][q] + bj[j]);
                *(ushortx4*)(Vt + (((size_t)((b << 4) + hh)) << 16) + (d << 10) + s) = pk;
            }
        }
    } else {
        unsigned short* dst = which ? Kb : Qb;
        const float sc = which ? 1.0f : 0.125f;   // fold 1/sqrt(64) into Q
#pragma unroll
        for (int i = 0; i < 4; ++i)
#pragma unroll
            for (int q = 0; q < 4; ++q) {
                const int m = m0 + (wm << 6) + (i << 4) + (g << 2) + q;
                const int b = m >> 10, s = m & 1023;
#pragma unroll
                for (int j = 0; j < 4; ++j) {
                    const int o = o0 + (wn << 6) + (j << 4) + ln;
                    const int d = o & 63, hh = (o >> 6) & 15;
                    dst[(((size_t)((b << 4) + hh)) << 16) + (s << 6) + d] =
                        f2b((acc[i][j][q] + bj[j]) * sc);
                }
            }
    }
}

// ---------------- k2: flash attention, K/E direct from L2, V prefetched in LDS ----------------
// block = 4 waves, (bh, 64 l-rows); wave w owns l-rows [16w,16w+16)
// per 64-key tile: S = QK^T + Uterm + Wterm (pre-sheared into S-layout buffers).
// K and E MFMA fragments are loaded DIRECTLY from global (L2-resident: per-XCD
// working set ~1MB K + 256KB E with the XCD swizzle) -> no staging barriers for them.
// Only V is staged (GLDS double-buffer, prefetch issued after barrier C, drained at D).
// dt pruning: U needs dt in [w,w+4], W needs dt in [3-w,7-w]  (20 MFMA vs 32).
// LDS elems (u16): V0 [0,4096) V1 [4096,8192)
//                  U' [8192,15104)  96 rows x 72 (sheared, guard rows absorb)
//                  W' [15104,21504) 64 rows x 100 (write stride 101 = shear fold)
//                  P  [21504,25600)
// total 25600 elems = 50 KiB -> 3 blocks/CU
__global__ __launch_bounds__(256, 3) void attn_mfma(
    const unsigned short* __restrict__ Qb, const unsigned short* __restrict__ Kb,
    const unsigned short* __restrict__ Vt, const unsigned short* __restrict__ Eb,
    const float* __restrict__ mask, float* __restrict__ outp)
{
    __shared__ __align__(16) unsigned short sm[25600];
    const int t = threadIdx.x, w = t >> 6;
    const int wu = __builtin_amdgcn_readfirstlane(w);   // wave-uniform in SGPR
    const int ln = t & 15, g = (t >> 4) & 3;
    const int bid = blockIdx.x;
    const int swz = ((bid & 7) << 7) | (bid >> 3);      // XCD-bijective (1024%8==0)
    const int bh = swz >> 4;
    const int l0 = (swz & 15) << 6;
    const int b = bh >> 4, h = bh & 15;
    const size_t hb = (size_t)bh << 16;
    const int x0 = (w << 4) + (g << 2);          // thread's base l-row

    // Q fragments direct from global (pre-scaled; L2-hot)
    const int qr = (w << 4) + ln;
    const short8 qa0 = *(const short8*)(Qb + hb + ((size_t)(l0 + qr) << 6) + (g << 3));
    const short8 qa1 = *(const short8*)(Qb + hb + ((size_t)(l0 + qr) << 6) + 32 + (g << 3));

    auto stageV = [&](int rb, int buf) {
#pragma unroll
        for (int p = 0; p < 2; ++p) {
            const int idx = (p << 8) + t;
            const int row = idx >> 3;            // = d
            const int c = (idx & 7) ^ (row & 7);
            GLDS16(Vt + hb + ((size_t)row << 10) + rb + (c << 3),
                   (char*)sm + (buf << 13) + (p << 12) + (w << 10));
        }
    };

    stageV(0, 0);                                // prologue: V(0) -> buf0

    floatx4 O[4];
    float mr[4], lr[4];
#pragma unroll
    for (int dt = 0; dt < 4; ++dt) O[dt] = (floatx4){0.f, 0.f, 0.f, 0.f};
#pragma unroll
    for (int q = 0; q < 4; ++q) { mr[q] = -1e30f; lr[q] = 0.f; }

    __syncthreads();                             // prologue staging visible

    for (int r0 = 0; r0 < SEQ; r0 += 64) {
        const int j0 = l0 - r0 + 960;            // E band start, in [0,1920]
        const int vb = (r0 >> 6) & 1;

        // K fragments direct from global (L2)
        short8 kf[4][2];
#pragma unroll
        for (int j = 0; j < 4; ++j) {
            const size_t kro = hb + ((size_t)(r0 + (j << 4) + ln) << 6);
            kf[j][0] = *(const short8*)(Kb + kro + (g << 3));
            kf[j][1] = *(const short8*)(Kb + kro + 32 + (g << 3));
        }
        const size_t kwo = hb + ((size_t)(r0 + (w << 4) + ln) << 6);
        const short8 ka0 = *(const short8*)(Kb + kwo + (g << 3));
        const short8 ka1 = *(const short8*)(Kb + kwo + 32 + (g << 3));

        floatx4 S[4];
#pragma unroll
        for (int j = 0; j < 4; ++j) {
            floatx4 z = (floatx4){0.f, 0.f, 0.f, 0.f};
            z = __builtin_amdgcn_mfma_f32_16x16x32_bf16(qa0, kf[j][0], z, 0, 0, 0);
            S[j] = __builtin_amdgcn_mfma_f32_16x16x32_bf16(qa1, kf[j][1], z, 0, 0, 0);
        }
        // band GEMMs, pruned per wave; E fragments direct from global (L2)
#pragma unroll
        for (int dt = 0; dt < 8; ++dt) {
            const bool doU = (dt >= wu) && (dt <= wu + 4);
            const bool doW = (dt >= 3 - wu) && (dt <= 7 - wu);
            if (!doU && !doW) continue;
            const size_t ero = (size_t)(j0 + (dt << 4) + ln) << 6;
            const short8 e0 = *(const short8*)(Eb + ero + (g << 3));
            const short8 e1 = *(const short8*)(Eb + ero + 32 + (g << 3));
            if (doU) {
                floatx4 z = (floatx4){0.f, 0.f, 0.f, 0.f};
                z = __builtin_amdgcn_mfma_f32_16x16x32_bf16(qa0, e0, z, 0, 0, 0);
                const floatx4 U = __builtin_amdgcn_mfma_f32_16x16x32_bf16(qa1, e1, z, 0, 0, 0);
                // cell (rr = ll-br+63, ll); rows rr+16 in [0,95] (guard rows absorb)
                int a = 8192 + (x0 - (dt << 4) - ln + 79) * 72 + x0;
#pragma unroll
                for (int q = 0; q < 4; ++q) { sm[a] = f2b(U[q]); a += 73; }
            }
            if (doW) {
                floatx4 z2 = (floatx4){0.f, 0.f, 0.f, 0.f};
                z2 = __builtin_amdgcn_mfma_f32_16x16x32_bf16(ka0, e0, z2, 0, 0, 0);
                const floatx4 Wv = __builtin_amdgcn_mfma_f32_16x16x32_bf16(ka1, e1, z2, 0, 0, 0);
                // cell (rW = x0+q, col = 16dt+ln+x0+q-47), col in [1,95] (guard cols absorb)
                int a = 15104 + x0 * 101 + (dt << 4) + ln - 47;
#pragma unroll
                for (int q = 0; q < 4; ++q) { sm[a] = f2b(Wv[q] * 0.125f); a += 101; }
            }
        }
        __syncthreads();                         // C: U'/W' visible; V[vb^1] dead

        if (r0 < 960) stageV(r0 + 64, vb ^ 1);   // prefetch next V (drains at D)

        // assemble scores: vector b64 reads + global mask (L2-hot)
        float Pw[4][4];
#pragma unroll
        for (int j = 0; j < 4; ++j) {
            const int rr = (j << 4) + ln;
            const float mk = mask[(b << 10) + r0 + rr];
            const ushortx4 u4 = *(const ushortx4*)&sm[8192 + (rr + 16) * 72 + x0];
            const ushortx4 w4 = *(const ushortx4*)&sm[15104 + rr * 100 + 16 + x0];
#pragma unroll
            for (int q = 0; q < 4; ++q)
                S[j][q] += b2f(u4[q]) + b2f(w4[q]) + mk;
        }
        // online softmax (unconditional rescale — round-2 proven form)
#pragma unroll
        for (int q = 0; q < 4; ++q) {
            float tm = fmaxf(fmaxf(S[0][q], S[1][q]), fmaxf(S[2][q], S[3][q]));
            tm = fmaxf(tm, __shfl_xor(tm, 1));
            tm = fmaxf(tm, __shfl_xor(tm, 2));
            tm = fmaxf(tm, __shfl_xor(tm, 4));
            tm = fmaxf(tm, __shfl_xor(tm, 8));
            const float mnew = fmaxf(mr[q], tm);
            const float al = __expf(mr[q] - mnew);
            float sum = 0.f;
#pragma unroll
            for (int j = 0; j < 4; ++j) {
                const float p = __expf(S[j][q] - mnew);
                Pw[j][q] = p; sum += p;
            }
            sum += __shfl_xor(sum, 1);
            sum += __shfl_xor(sum, 2);
            sum += __shfl_xor(sum, 4);
            sum += __shfl_xor(sum, 8);
            lr[q] = lr[q] * al + sum;
            mr[q] = mnew;
#pragma unroll
            for (int dt = 0; dt < 4; ++dt) O[dt][q] *= al;
        }
        // write P (bf16) into [l][r] swizzled tile
#pragma unroll
        for (int j = 0; j < 4; ++j) {
            const int rr = (j << 4) + ln;
#pragma unroll
            for (int q = 0; q < 4; ++q) {
                const int l = x0 + q;
                sm[21504 + (l << 6) + ((((rr >> 3) ^ (l & 7)) << 3)) + (rr & 7)] = f2b(Pw[j][q]);
            }
        }
        __syncthreads();                         // D: P visible; V prefetch drained

        const int pr = (w << 4) + ln;
        const short8 pa0 = *(const short8*)&sm[TADDR(21504, pr, g)];
        const short8 pa1 = *(const short8*)&sm[TADDR(21504, pr, 4 + g)];
        const int vbase = vb << 12;
#pragma unroll
        for (int dt = 0; dt < 4; ++dt) {
            const int vr = (dt << 4) + ln;       // = d row of V^T tile
            const short8 v0 = *(const short8*)&sm[TADDR(vbase, vr, g)];
            const short8 v1 = *(const short8*)&sm[TADDR(vbase, vr, 4 + g)];
            O[dt] = __builtin_amdgcn_mfma_f32_16x16x32_bf16(pa0, v0, O[dt], 0, 0, 0);
            O[dt] = __builtin_amdgcn_mfma_f32_16x16x32_bf16(pa1, v1, O[dt], 0, 0, 0);
        }
    }
    // normalize + write out[b, l0+l, h*64 + d]
#pragma unroll
    for (int dt = 0; dt < 4; ++dt)
#pragma unroll
        for (int q = 0; q < 4; ++q) {
            const int l = x0 + q;
            outp[((size_t)b << 20) + ((size_t)(l0 + l) << 10) + (h << 6) + (dt << 4) + ln]
                = O[dt][q] / lr[q];
        }
}

extern "C" void kernel_launch(void* const* d_in, const int* in_sizes, int n_in,
                              void* d_out, int out_size, void* d_ws, size_t ws_size,
                              hipStream_t stream)
{
    const float* hs   = (const float*)d_in[0];   // [4,1024,1024]
    const float* qkvw = (const float*)d_in[1];   // [3072,1024]
    const float* qkvb = (const float*)d_in[2];   // [3072]
    const float* demb = (const float*)d_in[3];   // [2047,64]
    const float* mask = (const float*)d_in[4];   // [4,1,1,1024]
    float* out = (float*)d_out;

    char* ws = (char*)d_ws;
    unsigned short* hsb = (unsigned short*)(ws);              // 8,388,608 B
    unsigned short* Wb  = (unsigned short*)(ws + 8388608);    // 6,291,456 B
    unsigned short* Eb  = (unsigned short*)(ws + 14680064);   //   262,016 B
    unsigned short* Qb  = (unsigned short*)(ws + 14942208);   // 8,388,608 B (pre-scaled)
    unsigned short* Kb  = (unsigned short*)(ws + 23330816);   // 8,388,608 B
    unsigned short* Vt  = (unsigned short*)(ws + 31719424);   // 8,388,608 B (transposed)

    cast_kernel<<<2048, 256, 0, stream>>>(hs, qkvw, demb, hsb, Wb, Eb);
    qkv_gemm<<<dim3(24, 32), 256, 0, stream>>>(hsb, Wb, qkvb, Qb, Kb, Vt);
    attn_mfma<<<1024, 256, 0, stream>>>(Qb, Kb, Vt, Eb, mask, out);
}

// Round 5
// 228.423 us; speedup vs baseline: 1.8134x; 1.8134x over previous
//
#include <hip/hip_runtime.h>

#define SEQ 1024
#define NH  16

typedef __attribute__((ext_vector_type(8))) short short8;
typedef __attribute__((ext_vector_type(4))) float floatx4;
typedef __attribute__((ext_vector_type(4))) unsigned short ushortx4;

// async global->LDS, 16B per lane; LDS dest = wave-uniform base + lane*16
#define GLDS16(gp, lp) __builtin_amdgcn_global_load_lds( \
    (const __attribute__((address_space(1))) void*)(gp), \
    (__attribute__((address_space(3))) void*)(lp), 16, 0, 0)

__device__ __forceinline__ unsigned short f2b(float f) {   // fp32 -> bf16 RNE
    union { float f; unsigned u; } v; v.f = f;
    unsigned r = (v.u + 0x7fffu + ((v.u >> 16) & 1u)) >> 16;
    return (unsigned short)r;
}
__device__ __forceinline__ float b2f(unsigned short h) {
    union { unsigned u; float f; } v; v.u = ((unsigned)h) << 16;
    return v.f;
}

// swizzled addr helper (element offsets in a 64-wide bf16 tile: 8 chunks of 16B/row)
#define TADDR(base, row, ch) ((base) + ((row) << 6) + ((((ch) ^ ((row) & 7))) << 3))

// ---------------- k0: fp32 -> bf16 casts ----------------
__global__ void cast_kernel(const float* __restrict__ hs, const float* __restrict__ W,
                            const float* __restrict__ E,
                            unsigned short* __restrict__ hsb,
                            unsigned short* __restrict__ Wb,
                            unsigned short* __restrict__ Eb)
{
    const int QH = 1048576, QW = 786432, QE = 32752;   // quads
    const int NT = QH + QW + QE;
    for (int q = blockIdx.x * 256 + threadIdx.x; q < NT; q += gridDim.x * 256) {
        const float* src; unsigned short* dst; int off;
        if (q < QH)           { src = hs; dst = hsb; off = q; }
        else if (q < QH + QW) { src = W;  dst = Wb;  off = q - QH; }
        else                  { src = E;  dst = Eb;  off = q - QH - QW; }
        const float4 v = *(const float4*)(src + (size_t)off * 4);
        ushortx4 o; o[0] = f2b(v.x); o[1] = f2b(v.y); o[2] = f2b(v.z); o[3] = f2b(v.w);
        *(ushortx4*)(dst + (size_t)off * 4) = o;
    }
}

// ---------------- k1: QKV projection, bf16 MFMA, NT layout ----------------
__global__ __launch_bounds__(256, 3) void qkv_gemm(
    const unsigned short* __restrict__ Ab, const unsigned short* __restrict__ Bb,
    const float* __restrict__ bias,
    unsigned short* __restrict__ Qb, unsigned short* __restrict__ Kb,
    unsigned short* __restrict__ Vt)
{
    __shared__ unsigned short sm[8192];          // A [0,4096), B [4096,8192) elems
    const int t = threadIdx.x, w = t >> 6;
    const int ln = t & 15, g = (t >> 4) & 3;
    const int wm = w >> 1, wn = w & 1;
    const int m0 = blockIdx.y << 7, o0 = blockIdx.x << 7;

    floatx4 acc[4][4];
#pragma unroll
    for (int i = 0; i < 4; ++i)
#pragma unroll
        for (int j = 0; j < 4; ++j) acc[i][j] = (floatx4){0.f, 0.f, 0.f, 0.f};

    auto stage = [&](int kb) {
#pragma unroll
        for (int p = 0; p < 2; ++p) {
            const int idx = (p << 8) + t;
            const int row = idx >> 2;
            const int c = (idx & 3) ^ ((row ^ (row >> 2)) & 3);
            GLDS16(Ab + (size_t)(m0 + row) * 1024 + kb + (c << 3),
                   (char*)sm + (p << 12) + (w << 10));
            GLDS16(Bb + (size_t)(o0 + row) * 1024 + kb + (c << 3),
                   (char*)sm + 8192 + (p << 12) + (w << 10));
        }
    };

    stage(0);
    for (int kb = 0;;) {
        __syncthreads();
        short8 af[4], bf_[4];
#pragma unroll
        for (int i = 0; i < 4; ++i) {
            const int r = (wm << 6) + (i << 4) + ln;
            af[i] = *(const short8*)&sm[(r << 5) + ((g ^ ((r ^ (r >> 2)) & 3)) << 3)];
        }
#pragma unroll
        for (int j = 0; j < 4; ++j) {
            const int r = (wn << 6) + (j << 4) + ln;
            bf_[j] = *(const short8*)&sm[4096 + (r << 5) + ((g ^ ((r ^ (r >> 2)) & 3)) << 3)];
        }
#pragma unroll
        for (int i = 0; i < 4; ++i)
#pragma unroll
            for (int j = 0; j < 4; ++j)
                acc[i][j] = __builtin_amdgcn_mfma_f32_16x16x32_bf16(af[i], bf_[j], acc[i][j], 0, 0, 0);
        kb += 32;
        if (kb >= 1024) break;
        __syncthreads();
        stage(kb);
    }

    const int which = o0 >> 10;     // 0=Q 1=K 2=V (block-uniform)
    float bj[4];
#pragma unroll
    for (int j = 0; j < 4; ++j) bj[j] = bias[o0 + (wn << 6) + (j << 4) + ln];

    if (which == 2) {               // V transposed: Vt[bh][d][s]
#pragma unroll
        for (int i = 0; i < 4; ++i) {
            const int m = m0 + (wm << 6) + (i << 4) + (g << 2);
            const int b = m >> 10, s = m & 1023;
#pragma unroll
            for (int j = 0; j < 4; ++j) {
                const int o = o0 + (wn << 6) + (j << 4) + ln;
                const int d = o & 63, hh = (o >> 6) & 15;
                ushortx4 pk;
#pragma unroll
                for (int q = 0; q < 4; ++q) pk[q] = f2b(acc[i][j][q] + bj[j]);
                *(ushortx4*)(Vt + (((size_t)((b << 4) + hh)) << 16) + (d << 10) + s) = pk;
            }
        }
    } else {
        unsigned short* dst = which ? Kb : Qb;
        const float sc = which ? 1.0f : 0.125f;   // fold 1/sqrt(64) into Q
#pragma unroll
        for (int i = 0; i < 4; ++i)
#pragma unroll
            for (int q = 0; q < 4; ++q) {
                const int m = m0 + (wm << 6) + (i << 4) + (g << 2) + q;
                const int b = m >> 10, s = m & 1023;
#pragma unroll
                for (int j = 0; j < 4; ++j) {
                    const int o = o0 + (wn << 6) + (j << 4) + ln;
                    const int d = o & 63, hh = (o >> 6) & 15;
                    dst[(((size_t)((b << 4) + hh)) << 16) + (s << 6) + d] =
                        f2b((acc[i][j][q] + bj[j]) * sc);
                }
            }
    }
}

// ---------------- k2: flash attention, 2 barriers/tile, K/E/V prefetched ----------------
// block = 4 waves, (bh, 64 l-rows); wave w owns l-rows [16w,16w+16)
// per 64-key tile: S = QK^T + Uterm + Wterm (pre-sheared into S-layout buffers).
// All staged operands (K, E, V) are prefetched for the NEXT tile right after
// barrier C; the drain lands at barrier D, hidden under scores+softmax+P (~400cy).
// E is a 128-row ring (phys = abs & 127): band slides 64 rows/tile, so only the
// 64 new rows are staged -> E traffic halved.
// dt pruning: U needs dt in [w,w+4], W needs dt in [3-w,7-w]  (20 MFMA vs 32).
// LDS elems (u16): K[0,4096) | V0[4096,8192) V1[8192,12288) | E-ring[12288,20480)
//                  U'[20480,27392) 96 rows x 72 (sheared, guard rows absorb)
//                  W'[27392,33792) 64 rows x 100 (write stride 101 = shear fold)
//                  P [33792,37888)
// total 37888 elems = 74 KiB -> 2 blocks/CU
__global__ __launch_bounds__(256, 2) void attn_mfma(
    const unsigned short* __restrict__ Qb, const unsigned short* __restrict__ Kb,
    const unsigned short* __restrict__ Vt, const unsigned short* __restrict__ Eb,
    const float* __restrict__ mask, float* __restrict__ outp)
{
    __shared__ __align__(16) unsigned short sm[37888];
    const int t = threadIdx.x, w = t >> 6;
    const int wu = __builtin_amdgcn_readfirstlane(w);   // wave-uniform in SGPR
    const int ln = t & 15, g = (t >> 4) & 3;
    const int bid = blockIdx.x;
    const int swz = ((bid & 7) << 7) | (bid >> 3);      // XCD-bijective (1024%8==0)
    const int bh = swz >> 4;
    const int l0 = (swz & 15) << 6;
    const int b = bh >> 4, h = bh & 15;
    const size_t hb = (size_t)bh << 16;
    const int x0 = (w << 4) + (g << 2);          // thread's base l-row

    // Q fragments direct from global (pre-scaled; L2-hot)
    const int qr = (w << 4) + ln;
    const short8 qa0 = *(const short8*)(Qb + hb + ((size_t)(l0 + qr) << 6) + (g << 3));
    const short8 qa1 = *(const short8*)(Qb + hb + ((size_t)(l0 + qr) << 6) + 32 + (g << 3));

    auto stageK = [&](int rb) {
#pragma unroll
        for (int p = 0; p < 2; ++p) {
            const int idx = (p << 8) + t;
            const int row = idx >> 3;
            const int c = (idx & 7) ^ (row & 7);
            GLDS16(Kb + hb + ((size_t)(rb + row) << 6) + (c << 3),
                   (char*)sm + (p << 12) + (w << 10));
        }
    };
    auto stageV = [&](int rb, int buf) {
#pragma unroll
        for (int p = 0; p < 2; ++p) {
            const int idx = (p << 8) + t;
            const int row = idx >> 3;            // = d
            const int c = (idx & 7) ^ (row & 7);
            GLDS16(Vt + hb + ((size_t)row << 10) + rb + (c << 3),
                   (char*)sm + 8192 + (buf << 13) + (p << 12) + (w << 10));
        }
    };
    auto stageE64 = [&](int j0n) {               // stage 64 new rows [j0n, j0n+64)
        const int ejn = j0n & 64;                // their phys half
#pragma unroll
        for (int p = 0; p < 2; ++p) {
            const int idx = (p << 8) + t;
            const int row = idx >> 3;            // phys row = ejn + row
            const int c = (idx & 7) ^ (row & 7);
            GLDS16(Eb + ((size_t)(j0n + row) << 6) + (c << 3),
                   (char*)sm + 24576 + (ejn << 7) + (p << 12) + (w << 10));
        }
    };

    // ---- prologue: stage K(0), full 128-row E window, V(0)->buf0 ----
    stageK(0);
    {
        const int j0p = l0 + 960, ejp = j0p & 64;
#pragma unroll
        for (int p = 0; p < 4; ++p) {
            const int idx = (p << 8) + t;
            const int prow = idx >> 3;           // phys row
            const int arow = j0p + (prow ^ ejp); // abs row with abs&127 == prow
            const int c = (idx & 7) ^ (prow & 7);
            GLDS16(Eb + ((size_t)arow << 6) + (c << 3),
                   (char*)sm + 24576 + (p << 12) + (w << 10));
        }
    }
    stageV(0, 0);

    floatx4 O[4];
    float mr[4], lr[4];
#pragma unroll
    for (int dt = 0; dt < 4; ++dt) O[dt] = (floatx4){0.f, 0.f, 0.f, 0.f};
#pragma unroll
    for (int q = 0; q < 4; ++q) { mr[q] = -1e30f; lr[q] = 0.f; }

    __syncthreads();                             // prologue staging visible

    for (int r0 = 0; r0 < SEQ; r0 += 64) {
        const int j0 = l0 - r0 + 960;            // E band start (abs), in [0,1920]
        const int ej = j0 & 64;
        const int vb = (r0 >> 6) & 1;

        // K fragments from LDS
        short8 kf[4][2];
#pragma unroll
        for (int j = 0; j < 4; ++j) {
            const int kr = (j << 4) + ln;
            kf[j][0] = *(const short8*)&sm[TADDR(0, kr, g)];
            kf[j][1] = *(const short8*)&sm[TADDR(0, kr, 4 + g)];
        }
        const int wr = (w << 4) + ln;            // W A-fragment (this wave's K rows)
        const short8 ka0 = *(const short8*)&sm[TADDR(0, wr, g)];
        const short8 ka1 = *(const short8*)&sm[TADDR(0, wr, 4 + g)];

        floatx4 S[4];
#pragma unroll
        for (int j = 0; j < 4; ++j) {
            floatx4 z = (floatx4){0.f, 0.f, 0.f, 0.f};
            z = __builtin_amdgcn_mfma_f32_16x16x32_bf16(qa0, kf[j][0], z, 0, 0, 0);
            S[j] = __builtin_amdgcn_mfma_f32_16x16x32_bf16(qa1, kf[j][1], z, 0, 0, 0);
        }
        // band GEMMs, pruned per wave; E from ring (phys = rel ^ ej)
#pragma unroll
        for (int dt = 0; dt < 8; ++dt) {
            const bool doU = (dt >= wu) && (dt <= wu + 4);
            const bool doW = (dt >= 3 - wu) && (dt <= 7 - wu);
            if (!doU && !doW) continue;
            const int ephys = ((dt << 4) + ln) ^ ej;
            const short8 e0 = *(const short8*)&sm[TADDR(12288, ephys, g)];
            const short8 e1 = *(const short8*)&sm[TADDR(12288, ephys, 4 + g)];
            if (doU) {
                floatx4 z = (floatx4){0.f, 0.f, 0.f, 0.f};
                z = __builtin_amdgcn_mfma_f32_16x16x32_bf16(qa0, e0, z, 0, 0, 0);
                const floatx4 U = __builtin_amdgcn_mfma_f32_16x16x32_bf16(qa1, e1, z, 0, 0, 0);
                // cell (rr = ll-br+63, ll); rows rr+16 in [0,95] (guard rows absorb)
                int a = 20480 + (x0 - (dt << 4) - ln + 79) * 72 + x0;
#pragma unroll
                for (int q = 0; q < 4; ++q) { sm[a] = f2b(U[q]); a += 73; }
            }
            if (doW) {
                floatx4 z2 = (floatx4){0.f, 0.f, 0.f, 0.f};
                z2 = __builtin_amdgcn_mfma_f32_16x16x32_bf16(ka0, e0, z2, 0, 0, 0);
                const floatx4 Wv = __builtin_amdgcn_mfma_f32_16x16x32_bf16(ka1, e1, z2, 0, 0, 0);
                // cell (rW = x0+q, col = 16dt+ln+x0+q-47), col in [1,95] (guard cols absorb)
                int a = 27392 + x0 * 101 + (dt << 4) + ln - 47;
#pragma unroll
                for (int q = 0; q < 4; ++q) { sm[a] = f2b(Wv[q] * 0.125f); a += 101; }
            }
        }
        __syncthreads();                         // C: U'/W' visible; K, E-old-half, V[vb^1] dead

        if (r0 < 960) {                          // prefetch next tile (drains at D)
            stageK(r0 + 64);
            stageE64(j0 - 64);
            stageV(r0 + 64, vb ^ 1);
        }

        // assemble scores: vector b64 reads + global mask (L2-hot)
        float Pw[4][4];
#pragma unroll
        for (int j = 0; j < 4; ++j) {
            const int rr = (j << 4) + ln;
            const float mk = mask[(b << 10) + r0 + rr];
            const ushortx4 u4 = *(const ushortx4*)&sm[20480 + (rr + 16) * 72 + x0];
            const ushortx4 w4 = *(const ushortx4*)&sm[27392 + rr * 100 + 16 + x0];
#pragma unroll
            for (int q = 0; q < 4; ++q)
                S[j][q] += b2f(u4[q]) + b2f(w4[q]) + mk;
        }
        // online softmax (unconditional rescale — proven form)
#pragma unroll
        for (int q = 0; q < 4; ++q) {
            float tm = fmaxf(fmaxf(S[0][q], S[1][q]), fmaxf(S[2][q], S[3][q]));
            tm = fmaxf(tm, __shfl_xor(tm, 1));
            tm = fmaxf(tm, __shfl_xor(tm, 2));
            tm = fmaxf(tm, __shfl_xor(tm, 4));
            tm = fmaxf(tm, __shfl_xor(tm, 8));
            const float mnew = fmaxf(mr[q], tm);
            const float al = __expf(mr[q] - mnew);
            float sum = 0.f;
#pragma unroll
            for (int j = 0; j < 4; ++j) {
                const float p = __expf(S[j][q] - mnew);
                Pw[j][q] = p; sum += p;
            }
            sum += __shfl_xor(sum, 1);
            sum += __shfl_xor(sum, 2);
            sum += __shfl_xor(sum, 4);
            sum += __shfl_xor(sum, 8);
            lr[q] = lr[q] * al + sum;
            mr[q] = mnew;
#pragma unroll
            for (int dt = 0; dt < 4; ++dt) O[dt][q] *= al;
        }
        // write P (bf16) into [l][r] swizzled tile
#pragma unroll
        for (int j = 0; j < 4; ++j) {
            const int rr = (j << 4) + ln;
#pragma unroll
            for (int q = 0; q < 4; ++q) {
                const int l = x0 + q;
                sm[33792 + (l << 6) + ((((rr >> 3) ^ (l & 7)) << 3)) + (rr & 7)] = f2b(Pw[j][q]);
            }
        }
        __syncthreads();                         // D: P visible; prefetch drained

        const int pr = (w << 4) + ln;
        const short8 pa0 = *(const short8*)&sm[TADDR(33792, pr, g)];
        const short8 pa1 = *(const short8*)&sm[TADDR(33792, pr, 4 + g)];
        const int vbase = 4096 + (vb << 12);
#pragma unroll
        for (int dt = 0; dt < 4; ++dt) {
            const int vr = (dt << 4) + ln;       // = d row of V^T tile
            const short8 v0 = *(const short8*)&sm[TADDR(vbase, vr, g)];
            const short8 v1 = *(const short8*)&sm[TADDR(vbase, vr, 4 + g)];
            O[dt] = __builtin_amdgcn_mfma_f32_16x16x32_bf16(pa0, v0, O[dt], 0, 0, 0);
            O[dt] = __builtin_amdgcn_mfma_f32_16x16x32_bf16(pa1, v1, O[dt], 0, 0, 0);
        }
    }
    // normalize + write out[b, l0+l, h*64 + d]
#pragma unroll
    for (int dt = 0; dt < 4; ++dt)
#pragma unroll
        for (int q = 0; q < 4; ++q) {
            const int l = x0 + q;
            outp[((size_t)b << 20) + ((size_t)(l0 + l) << 10) + (h << 6) + (dt << 4) + ln]
                = O[dt][q] / lr[q];
        }
}

extern "C" void kernel_launch(void* const* d_in, const int* in_sizes, int n_in,
                              void* d_out, int out_size, void* d_ws, size_t ws_size,
                              hipStream_t stream)
{
    const float* hs   = (const float*)d_in[0];   // [4,1024,1024]
    const float* qkvw = (const float*)d_in[1];   // [3072,1024]
    const float* qkvb = (const float*)d_in[2];   // [3072]
    const float* demb = (const float*)d_in[3];   // [2047,64]
    const float* mask = (const float*)d_in[4];   // [4,1,1,1024]
    float* out = (float*)d_out;

    char* ws = (char*)d_ws;
    unsigned short* hsb = (unsigned short*)(ws);              // 8,388,608 B
    unsigned short* Wb  = (unsigned short*)(ws + 8388608);    // 6,291,456 B
    unsigned short* Eb  = (unsigned short*)(ws + 14680064);   //   262,016 B
    unsigned short* Qb  = (unsigned short*)(ws + 14942208);   // 8,388,608 B (pre-scaled)
    unsigned short* Kb  = (unsigned short*)(ws + 23330816);   // 8,388,608 B
    unsigned short* Vt  = (unsigned short*)(ws + 31719424);   // 8,388,608 B (transposed)

    cast_kernel<<<2048, 256, 0, stream>>>(hs, qkvw, demb, hsb, Wb, Eb);
    qkv_gemm<<<dim3(24, 32), 256, 0, stream>>>(hsb, Wb, qkvb, Qb, Kb, Vt);
    attn_mfma<<<1024, 256, 0, stream>>>(Qb, Kb, Vt, Eb, mask, out);
}